// Round 14
// baseline (195.838 us; speedup 1.0000x reference)
//
#include <hip/hip_runtime.h>
#include <hip/hip_bf16.h>

// FeatureProcessingBlock: per 64x64 window, Out = sum_t Cs_t^T ( Hs_t^T @ X_c @ Ws_t )
// R14 = R11 + producer/consumer wave specialization:
//   region R(s): waves0-3 do B(s) (LDS-heavy) || waves4-7 do A(s+1) (global/VALU)
//   -> each SIMD pairs one B-wave with one A-wave (complementary pipes overlap).
//   Y1F dbuf by chunk parity (2x48K). B-waves cover all 8 channels -> Zb writes
//   are full-line b128 (bank-minimal); Zb t-lines [3t][1024px][16B] keep C-reads
//   minimal; k=t*8+c so Cf/C-phase code = R11. Divergent wave-uniform loops with
//   equal barrier counts (legal: per-wave barrier arrival).

typedef __attribute__((ext_vector_type(8))) short short8;
typedef __attribute__((ext_vector_type(4))) short short4v;
typedef __attribute__((ext_vector_type(4))) float float4v;

#define SMEM_BYTES 161296
// Y1F @0: [2 buf][3t*8c][2 sv][64 lane][16B] = 98304
// Zb @98304: [3 t][1024 px][16B] = 49152   (slot k=t*8+c at byte 2c)
// Cf @147456: [18 ss*m][16 lc][48B] = 13824 | z16 @161280: 16B zeros

static __device__ __forceinline__ unsigned short f2bf(float f) {
  return __builtin_bit_cast(unsigned short, __float2bfloat16(f));
}
// LDS-only barrier: orders ds ops, leaves global loads in flight (T4).
static __device__ __forceinline__ void wg_barrier_lds() {
  asm volatile("s_waitcnt lgkmcnt(0)" ::: "memory");
  __builtin_amdgcn_s_barrier();
  asm volatile("" ::: "memory");
}

__global__ __launch_bounds__(512, 2)
void fpb14(const float* __restrict__ x, const float* __restrict__ Ws,
           const float* __restrict__ Hsm, const float* __restrict__ Cs,
           float* __restrict__ out) {
  extern __shared__ char smem[];
  char* Y1F = smem;
  char* Zb  = smem + 98304;
  char* Cf  = smem + 147456;
  char* z16 = smem + 161280;

  int wid = (blockIdx.x & 7) * 128 + (blockIdx.x >> 3);  // XCD swizzle
  int window = wid >> 2, tile = wid & 3;
  int b = window >> 6, p = (window >> 3) & 7, q = window & 7;
  int j0 = tile * 16;

  int tid = threadIdx.x, lane = tid & 63, wave = tid >> 6;
  int lq = lane >> 4, lc = lane & 15;

  if (tid < 4) ((unsigned int*)z16)[tid] = 0;

  // Cf init (all waves): row (ss*3+m, lc); k=t*8+c -> lane lq holds t=lq, e=c
  for (int idx = wave; idx < 18; idx += 8) {
    int ss = idx / 3, m = idx - 3 * ss;
    if (lq < 3) {
      short8 v;
      #pragma unroll
      for (int e = 0; e < 8; ++e)
        v[e] = (short)f2bf(Cs[lq * 2304 + (8 * ss + e) * 48 + 16 * m + lc]);
      *(short8*)(Cf + (idx * 16 + lc) * 48 + lq * 16) = v;
    }
  }

  float4v acc[3][8];
  #pragma unroll
  for (int m = 0; m < 3; ++m)
    #pragma unroll
    for (int i = 0; i < 8; ++i) acc[m][i] = float4v{0.f, 0.f, 0.f, 0.f};

  // ---- C-phase (all waves), identical to R11 but Zb t-lines ----
  #define CBLOCK(s_) do {                                                     \
    short8 cf_[3];                                                            \
    _Pragma("unroll")                                                         \
    for (int m_ = 0; m_ < 3; ++m_) {                                          \
      const char* cs_ = (lq < 3) ? (Cf + (((s_) * 3 + m_) * 16 + lc) * 48 + lq * 16) : z16; \
      cf_[m_] = *(const short8*)cs_;                                          \
    }                                                                         \
    _Pragma("unroll")                                                         \
    for (int i_ = 0; i_ < 8; ++i_) {                                          \
      int px_ = 16 * (wave + 8 * i_) + lc;                                    \
      const char* zs_ = (lq < 3) ? (Zb + lq * 16384 + px_ * 16) : z16;        \
      short8 zf_ = *(const short8*)zs_;                                       \
      acc[0][i_] = __builtin_amdgcn_mfma_f32_16x16x32_bf16(cf_[0], zf_, acc[0][i_], 0, 0, 0); \
      acc[1][i_] = __builtin_amdgcn_mfma_f32_16x16x32_bf16(cf_[1], zf_, acc[1][i_], 0, 0, 0); \
      acc[2][i_] = __builtin_amdgcn_mfma_f32_16x16x32_bf16(cf_[2], zf_, acc[2][i_], 0, 0, 0); \
    }                                                                         \
  } while (0)

  if (wave < 4) {
    // ================= B/consumer waves: mt = wave =================
    int mt = wave;
    short8 hsf[3][2];
    #pragma unroll
    for (int t = 0; t < 3; ++t)
      #pragma unroll
      for (int sv = 0; sv < 2; ++sv) {
        short8 bb;
        #pragma unroll
        for (int e = 0; e < 8; ++e)
          bb[e] = (short)f2bf(Hsm[t * 4096 + (32 * sv + 8 * lq + e) * 64 + 16 * mt + lc]);
        hsf[t][sv] = bb;
      }
    wg_barrier_lds();   // matches A-branch post-A(0) barrier

    #pragma unroll 1
    for (int s = 0; s < 6; ++s) {
      // B(s): read Y1F[s&1] (all 8 channels), write Zb full 16B lines
      const char* yb = Y1F + (s & 1) * 49152;
      #pragma unroll
      for (int t = 0; t < 3; ++t) {
        float4v dd[8];
        #pragma unroll
        for (int cl = 0; cl < 8; ++cl) {
          const char* ybs = yb + ((t * 8 + cl) * 2) * 1024 + lane * 16;
          short8 y0 = *(const short8*)ybs;
          short8 y1 = *(const short8*)(ybs + 1024);
          float4v d = {0.f, 0.f, 0.f, 0.f};
          d = __builtin_amdgcn_mfma_f32_16x16x32_bf16(hsf[t][0], y0, d, 0, 0, 0);
          d = __builtin_amdgcn_mfma_f32_16x16x32_bf16(hsf[t][1], y1, d, 0, 0, 0);
          dd[cl] = d;
        }
        #pragma unroll
        for (int r = 0; r < 4; ++r) {
          short8 v;
          #pragma unroll
          for (int e = 0; e < 8; ++e) v[e] = (short)f2bf(dd[e][r]);
          int px = (16 * mt + 4 * lq + r) * 16 + lc;
          *(short8*)(Zb + t * 16384 + px * 16) = v;
        }
      }
      wg_barrier_lds();
      CBLOCK(s);
      if (s < 5) wg_barrier_lds();
    }
  } else {
    // ================= A/producer waves: channels {aIdx, aIdx+4} =================
    int aIdx = wave - 4;
    short8 wsf[3][2];
    #pragma unroll
    for (int t = 0; t < 3; ++t)
      #pragma unroll
      for (int sv = 0; sv < 2; ++sv) {
        short8 aa;
        #pragma unroll
        for (int e = 0; e < 8; ++e)
          aa[e] = (short)f2bf(Ws[t * 4096 + (32 * sv + 8 * lq + e) * 64 + j0 + lc]);
        wsf[t][sv] = aa;
      }

    const float* xwin = x + (((size_t)b * 48) * 512 + p * 64) * 512 + q * 64
                          + (size_t)lc * 512 + 8 * lq;
    const float* xA0 = xwin + (size_t)aIdx * 262144;        // channel aIdx
    const float* xA1 = xwin + (size_t)(aIdx + 4) * 262144;  // channel aIdx+4

    float4v fin[2][8];  // slot = h-half; holds one channel-half (8 float4)
    #define LOADQ(h_, base_, s_) do {                                          \
      const float* r0_ = (base_) + (size_t)(s_) * 2097152 + (size_t)(32 * (h_)) * 512; \
      fin[h_][0] = *(const float4v*)(r0_);      fin[h_][1] = *(const float4v*)(r0_ + 4); \
      fin[h_][2] = *(const float4v*)(r0_ + 32); fin[h_][3] = *(const float4v*)(r0_ + 36); \
      const float* r1_ = r0_ + 8192;                                           \
      fin[h_][4] = *(const float4v*)(r1_);      fin[h_][5] = *(const float4v*)(r1_ + 4); \
      fin[h_][6] = *(const float4v*)(r1_ + 32); fin[h_][7] = *(const float4v*)(r1_ + 36); \
    } while (0)

    // quarter (chi,h) of A(s): consume fin[h], refill per schedule, MFMA+store
    #define AQUARTER(chi_, h_, s_) do {                                        \
      short8 af_[4];                                                           \
      _Pragma("unroll")                                                        \
      for (int j2_ = 0; j2_ < 2; ++j2_) {                                      \
        short8 a0_, a1_;                                                       \
        _Pragma("unroll")                                                      \
        for (int e2_ = 0; e2_ < 4; ++e2_) {                                    \
          a0_[e2_]   = (short)f2bf(fin[h_][4*j2_+0][e2_]);                     \
          a0_[4+e2_] = (short)f2bf(fin[h_][4*j2_+1][e2_]);                     \
          a1_[e2_]   = (short)f2bf(fin[h_][4*j2_+2][e2_]);                     \
          a1_[4+e2_] = (short)f2bf(fin[h_][4*j2_+3][e2_]);                     \
        }                                                                      \
        af_[2*j2_] = a0_; af_[2*j2_+1] = a1_;                                  \
      }                                                                        \
      if ((chi_) == 0) { LOADQ(h_, xA1, (s_)); }                               \
      else if ((s_) < 5) { LOADQ(h_, xA0, (s_) + 1); }                         \
      {                                                                        \
        int ch_ = aIdx + 4 * (chi_);                                           \
        char* ybuf_ = Y1F + ((s_) & 1) * 49152;                                \
        _Pragma("unroll")                                                      \
        for (int j2_ = 0; j2_ < 2; ++j2_) {                                    \
          int mA_  = 2 * (h_) + j2_;                                           \
          int lqp_ = (2 * mA_ + (lq >> 1)) & 3;                                \
          int eo_  = (lq & 1) * 8;                                             \
          _Pragma("unroll")                                                    \
          for (int t_ = 0; t_ < 3; ++t_) {                                     \
            float4v d_ = {0.f, 0.f, 0.f, 0.f};                                 \
            d_ = __builtin_amdgcn_mfma_f32_16x16x32_bf16(af_[2*j2_],   wsf[t_][0], d_, 0, 0, 0); \
            d_ = __builtin_amdgcn_mfma_f32_16x16x32_bf16(af_[2*j2_+1], wsf[t_][1], d_, 0, 0, 0); \
            short4v pv_;                                                       \
            pv_[0] = (short)f2bf(d_[0]); pv_[1] = (short)f2bf(d_[1]);          \
            pv_[2] = (short)f2bf(d_[2]); pv_[3] = (short)f2bf(d_[3]);          \
            *(short4v*)(ybuf_ + ((t_ * 8 + ch_) * 2 + (h_)) * 1024             \
                              + (lqp_ * 16 + lc) * 16 + eo_) = pv_;            \
          }                                                                    \
        }                                                                      \
      }                                                                        \
    } while (0)

    #define ABLOCK(s_) do {                                                    \
      AQUARTER(0, 0, (s_)); AQUARTER(0, 1, (s_));                              \
      AQUARTER(1, 0, (s_)); AQUARTER(1, 1, (s_));                              \
    } while (0)

    LOADQ(0, xA0, 0);
    LOADQ(1, xA0, 0);
    ABLOCK(0);
    wg_barrier_lds();   // Y1F[0] ready for B(0)

    #pragma unroll 1
    for (int s = 0; s < 6; ++s) {
      if (s < 5) ABLOCK(s + 1);
      wg_barrier_lds();
      CBLOCK(s);
      if (s < 5) wg_barrier_lds();
    }
  }

  // ---- epilogue: fully static stores (identical R11) ----
  #pragma unroll
  for (int m = 0; m < 3; ++m)
    #pragma unroll
    for (int i = 0; i < 8; ++i) {
      int n = wave + 8 * i;
      size_t rowbase = (((size_t)(b * 48 + 16 * m + 4 * lq)) * 512 + p * 64 + n) * 512
                       + q * 64 + j0 + lc;
      #pragma unroll
      for (int r = 0; r < 4; ++r)
        out[rowbase + (size_t)r * 262144] = acc[m][i][r];
    }
}

extern "C" void kernel_launch(void* const* d_in, const int* in_sizes, int n_in,
                              void* d_out, int out_size, void* d_ws, size_t ws_size,
                              hipStream_t stream) {
  (void)in_sizes; (void)n_in; (void)d_ws; (void)ws_size; (void)out_size;
  const float* x   = (const float*)d_in[0];
  const float* Ws  = (const float*)d_in[1];
  const float* Hsm = (const float*)d_in[2];
  const float* Cs  = (const float*)d_in[3];
  float* out = (float*)d_out;
  (void)hipFuncSetAttribute((const void*)fpb14,
                            hipFuncAttributeMaxDynamicSharedMemorySize, SMEM_BYTES);
  fpb14<<<dim3(1024), dim3(512), SMEM_BYTES, stream>>>(x, Ws, Hsm, Cs, out);
}

// Round 15
// 185.171 us; speedup vs baseline: 1.0576x; 1.0576x over previous
//
#include <hip/hip_runtime.h>
#include <hip/hip_bf16.h>

// FeatureProcessingBlock: per 64x64 window, Out = sum_t Cs_t^T ( Hs_t^T @ X_c @ Ws_t )
// R15 = R11 (155.7us) + ONE delta: Y1F double-buffered (+48K) and A's two h-halves
//   split across regions so B never runs alone:
//     {B(s); A(s+1).h0} | bar | {C(s); A(s+1).h1} | bar
//   Same live-register set as R11 (fin[2][8] unchanged), same 12 barriers/window,
//   same Zb/Cf layouts, LDS-only barriers (T4).

typedef __attribute__((ext_vector_type(8))) short short8;
typedef __attribute__((ext_vector_type(4))) short short4v;
typedef __attribute__((ext_vector_type(4))) float float4v;

#define SMEM_BYTES 161296
// Y1F @0: [2 buf][3t*8c][2 sv][64 lane][16B] = 98304  (B-operand fragment layout)
// Zb @98304: [1024 px][48 B] = 49152  (slot k=t*8+cl at byte 2k)
// Cf @147456: [18 ss*m][16 lc][48B] = 13824 | z16 @161280: 16 B zeros

static __device__ __forceinline__ unsigned short f2bf(float f) {
  return __builtin_bit_cast(unsigned short, __float2bfloat16(f));
}
static __device__ __forceinline__ unsigned long long pk4(float a, float b, float c, float d) {
  unsigned long long lo = (unsigned int)((unsigned int)f2bf(a) | ((unsigned int)f2bf(b) << 16));
  unsigned long long hi = (unsigned int)((unsigned int)f2bf(c) | ((unsigned int)f2bf(d) << 16));
  return lo | (hi << 32);
}
// LDS-only barrier: orders ds ops, leaves global loads in flight (T4).
static __device__ __forceinline__ void wg_barrier_lds() {
  asm volatile("s_waitcnt lgkmcnt(0)" ::: "memory");
  __builtin_amdgcn_s_barrier();
  asm volatile("" ::: "memory");
}

__global__ __launch_bounds__(512, 2)
void fpb15(const float* __restrict__ x, const float* __restrict__ Ws,
           const float* __restrict__ Hsm, const float* __restrict__ Cs,
           float* __restrict__ out) {
  extern __shared__ char smem[];
  char* Y1F = smem;                  // + (chunk&1)*49152
  char* Zb  = smem + 98304;
  char* Cf  = smem + 147456;
  char* z16 = smem + 161280;

  int wid = (blockIdx.x & 7) * 128 + (blockIdx.x >> 3);  // XCD swizzle
  int window = wid >> 2, tile = wid & 3;
  int b = window >> 6, p = (window >> 3) & 7, q = window & 7;
  int j0 = tile * 16;

  int tid = threadIdx.x, lane = tid & 63, wave = tid >> 6;
  int lq = lane >> 4, lc = lane & 15;
  int mt = wave & 3, cp = wave >> 2;

  if (tid < 4) ((unsigned int*)z16)[tid] = 0;

  // Cf init (identical R11)
  for (int idx = wave; idx < 18; idx += 8) {
    int ss = idx / 3, m = idx - 3 * ss;
    if (lq < 3) {
      short8 v;
      #pragma unroll
      for (int e = 0; e < 8; ++e)
        v[e] = (short)f2bf(Cs[lq * 2304 + (8 * ss + e) * 48 + 16 * m + lc]);
      *(short8*)(Cf + (idx * 16 + lc) * 48 + lq * 16) = v;
    }
  }

  // persistent factor fragments (identical R11)
  short8 wsf[3][2], hsf[3][2];
  #pragma unroll
  for (int t = 0; t < 3; ++t)
    #pragma unroll
    for (int sv = 0; sv < 2; ++sv) {
      short8 aa, bb;
      #pragma unroll
      for (int e = 0; e < 8; ++e) {
        int k = 32 * sv + 8 * lq + e;
        aa[e] = (short)f2bf(Ws [t * 4096 + k * 64 + j0 + lc]);      // B: Ws[w][W']
        bb[e] = (short)f2bf(Hsm[t * 4096 + k * 64 + 16 * mt + lc]); // A: Hs^T[H'][h]
      }
      wsf[t][sv] = aa; hsf[t][sv] = bb;
    }

  float4v acc[3][8];
  #pragma unroll
  for (int m = 0; m < 3; ++m)
    #pragma unroll
    for (int i = 0; i < 8; ++i) acc[m][i] = float4v{0.f, 0.f, 0.f, 0.f};

  // A-stage: wave = c (within chunk); rows 16*mA+lc (mA=2h+j2), cols 8*lq(+32)
  const float* xbase = x + (((size_t)b * 48) * 512 + p * 64) * 512 + q * 64
                         + (size_t)wave * 262144 + (size_t)lc * 512 + 8 * lq;

  float4v fin[2][8];   // fin[h] = rows 32h..32h+31 of this wave's channel

  #define LOADFIN(h_, s_) do {                                     \
    const float* src_ = xbase + (size_t)(s_) * 2097152             \
                              + (size_t)(32 * (h_)) * 512;         \
    _Pragma("unroll")                                              \
    for (int j2_ = 0; j2_ < 2; ++j2_) {                            \
      const float* r_ = src_ + (size_t)(16 * j2_) * 512;           \
      fin[h_][4*j2_+0] = *(const float4v*)(r_);                    \
      fin[h_][4*j2_+1] = *(const float4v*)(r_ + 4);                \
      fin[h_][4*j2_+2] = *(const float4v*)(r_ + 32);               \
      fin[h_][4*j2_+3] = *(const float4v*)(r_ + 36);               \
    }                                                              \
  } while (0)

  // A half-block: consume fin[h] for chunk st_, refill fin[h] <- chunk st_+1
  #define AHALF(h_, st_) do {                                                 \
    char* ybuf_ = Y1F + ((st_) & 1) * 49152;                                  \
    short8 af_[4];                                                            \
    _Pragma("unroll")                                                         \
    for (int j2_ = 0; j2_ < 2; ++j2_) {                                       \
      short8 a0_, a1_;                                                        \
      _Pragma("unroll")                                                       \
      for (int e2_ = 0; e2_ < 4; ++e2_) {                                     \
        a0_[e2_]   = (short)f2bf(fin[h_][4*j2_+0][e2_]);                      \
        a0_[4+e2_] = (short)f2bf(fin[h_][4*j2_+1][e2_]);                      \
        a1_[e2_]   = (short)f2bf(fin[h_][4*j2_+2][e2_]);                      \
        a1_[4+e2_] = (short)f2bf(fin[h_][4*j2_+3][e2_]);                      \
      }                                                                       \
      af_[2*j2_] = a0_; af_[2*j2_+1] = a1_;                                   \
    }                                                                         \
    if ((st_) < 5) LOADFIN(h_, (st_) + 1);                                    \
    _Pragma("unroll")                                                         \
    for (int j2_ = 0; j2_ < 2; ++j2_) {                                       \
      int mA_  = 2 * (h_) + j2_;                                              \
      int sv_  = mA_ >> 1;                                                    \
      int lqp_ = (2 * mA_ + (lq >> 1)) & 3;   /* R5/R11-verified mapping */   \
      int eo_  = (lq & 1) * 8;                                                \
      _Pragma("unroll")                                                       \
      for (int t_ = 0; t_ < 3; ++t_) {                                        \
        float4v d_ = {0.f, 0.f, 0.f, 0.f};                                    \
        d_ = __builtin_amdgcn_mfma_f32_16x16x32_bf16(af_[2*j2_],   wsf[t_][0], d_, 0, 0, 0); \
        d_ = __builtin_amdgcn_mfma_f32_16x16x32_bf16(af_[2*j2_+1], wsf[t_][1], d_, 0, 0, 0); \
        short4v pv_;                                                          \
        pv_[0] = (short)f2bf(d_[0]); pv_[1] = (short)f2bf(d_[1]);             \
        pv_[2] = (short)f2bf(d_[2]); pv_[3] = (short)f2bf(d_[3]);             \
        *(short4v*)(ybuf_ + ((t_ * 8 + wave) * 2 + sv_) * 1024                \
                          + (lqp_ * 16 + lc) * 16 + eo_) = pv_;               \
      }                                                                       \
    }                                                                         \
  } while (0)

  // ---- prologue: A(0) fully, then barrier ----
  LOADFIN(0, 0);
  LOADFIN(1, 0);
  wg_barrier_lds();   // Cf/z16 init visible before any cross-wave read
  AHALF(0, 0);
  AHALF(1, 0);
  wg_barrier_lds();   // Y1F[0] ready for B(0)

  #pragma unroll 1
  for (int s = 0; s < 6; ++s) {
    // ==== region 1: B(s) + A(s+1).h0 ====
    {
      const char* yb = Y1F + (s & 1) * 49152;
      #pragma unroll
      for (int t = 0; t < 3; ++t) {
        float4v dB[4];
        #pragma unroll
        for (int cj = 0; cj < 4; ++cj) {
          const char* ybs = yb + ((t * 8 + 4 * cp + cj) * 2) * 1024 + lane * 16;
          short8 y0 = *(const short8*)ybs;
          short8 y1 = *(const short8*)(ybs + 1024);
          float4v dd = {0.f, 0.f, 0.f, 0.f};
          dd = __builtin_amdgcn_mfma_f32_16x16x32_bf16(hsf[t][0], y0, dd, 0, 0, 0);
          dd = __builtin_amdgcn_mfma_f32_16x16x32_bf16(hsf[t][1], y1, dd, 0, 0, 0);
          dB[cj] = dd;
        }
        #pragma unroll
        for (int r = 0; r < 4; ++r) {
          int px = (16 * mt + 4 * lq + r) * 16 + lc;
          *(unsigned long long*)(Zb + px * 48 + 16 * t + 8 * cp) =
              pk4(dB[0][r], dB[1][r], dB[2][r], dB[3][r]);
        }
      }
      if (s < 5) AHALF(0, s + 1);
    }
    wg_barrier_lds();   // Zb ready for C; A.h0 writes ordered for B(s+1)

    // ==== region 2: C(s) + A(s+1).h1 ====
    {
      short8 cf[3];
      #pragma unroll
      for (int m = 0; m < 3; ++m) {
        const char* csrc = (lq < 3) ? (Cf + ((s * 3 + m) * 16 + lc) * 48 + lq * 16) : z16;
        cf[m] = *(const short8*)csrc;
      }
      #pragma unroll
      for (int i = 0; i < 8; ++i) {
        int px = 16 * (wave + 8 * i) + lc;
        const char* zsrc = (lq < 3) ? (Zb + px * 48 + 16 * lq) : z16;
        short8 zf = *(const short8*)zsrc;
        acc[0][i] = __builtin_amdgcn_mfma_f32_16x16x32_bf16(cf[0], zf, acc[0][i], 0, 0, 0);
        acc[1][i] = __builtin_amdgcn_mfma_f32_16x16x32_bf16(cf[1], zf, acc[1][i], 0, 0, 0);
        acc[2][i] = __builtin_amdgcn_mfma_f32_16x16x32_bf16(cf[2], zf, acc[2][i], 0, 0, 0);
      }
      if (s < 5) AHALF(1, s + 1);
    }
    wg_barrier_lds();   // C's Zb reads + A.h1 writes ordered before next B
  }

  // ---- epilogue: fully static stores (identical R11) ----
  #pragma unroll
  for (int m = 0; m < 3; ++m)
    #pragma unroll
    for (int i = 0; i < 8; ++i) {
      int n = wave + 8 * i;
      size_t rowbase = (((size_t)(b * 48 + 16 * m + 4 * lq)) * 512 + p * 64 + n) * 512
                       + q * 64 + j0 + lc;
      #pragma unroll
      for (int r = 0; r < 4; ++r)
        out[rowbase + (size_t)r * 262144] = acc[m][i][r];
    }
}

extern "C" void kernel_launch(void* const* d_in, const int* in_sizes, int n_in,
                              void* d_out, int out_size, void* d_ws, size_t ws_size,
                              hipStream_t stream) {
  (void)in_sizes; (void)n_in; (void)d_ws; (void)ws_size; (void)out_size;
  const float* x   = (const float*)d_in[0];
  const float* Ws  = (const float*)d_in[1];
  const float* Hsm = (const float*)d_in[2];
  const float* Cs  = (const float*)d_in[3];
  float* out = (float*)d_out;
  (void)hipFuncSetAttribute((const void*)fpb15,
                            hipFuncAttributeMaxDynamicSharedMemorySize, SMEM_BYTES);
  fpb15<<<dim3(1024), dim3(512), SMEM_BYTES, stream>>>(x, Ws, Hsm, Cs, out);
}

// Round 16
// 155.759 us; speedup vs baseline: 1.2573x; 1.1888x over previous
//
#include <hip/hip_runtime.h>
#include <hip/hip_bf16.h>

// FeatureProcessingBlock: per 64x64 window, Out = sum_t Cs_t^T ( Hs_t^T @ X_c @ Ws_t )
// FINAL = R11 (best of 15 rounds, 155.7us):
//   - all three contractions on MFMA 16x16x32 bf16
//   - Y1 fragment-major (A-phase writes B-operand frags directly: 2-way writes,
//     linear lane*16 b128 reads)
//   - Zb 48B rows, k=t*8+cl; Cf zero-baked; z16 stub for lq==3
//   - LDS-only barriers {s_waitcnt lgkmcnt(0); s_barrier}: global prefetch
//     stays in flight across barriers (T4)
//   - 2-slot register prefetch covering a full chunk of latency
//   - XCD-swizzled 1024-wg grid, 512 threads, 2 waves/SIMD (reg-capped by the
//     96-f32 accumulator -- structural; every overlap attempt spilled)

typedef __attribute__((ext_vector_type(8))) short short8;
typedef __attribute__((ext_vector_type(4))) short short4v;
typedef __attribute__((ext_vector_type(4))) float float4v;

#define SMEM_BYTES 112144
// Y1F @0: [3t*8c][2 sv][64 lane][16B] = 49152  (B-operand fragment layout)
// Zb @49152: [1024 px][48 B] = 49152  (slot k=t*8+cl at byte 2k)
// Cf @98304: [18 ss*m][16 lc][48 B] = 13824 | z16 @112128: 16 B zeros

static __device__ __forceinline__ unsigned short f2bf(float f) {
  return __builtin_bit_cast(unsigned short, __float2bfloat16(f));
}
static __device__ __forceinline__ unsigned long long pk4(float a, float b, float c, float d) {
  unsigned long long lo = (unsigned int)((unsigned int)f2bf(a) | ((unsigned int)f2bf(b) << 16));
  unsigned long long hi = (unsigned int)((unsigned int)f2bf(c) | ((unsigned int)f2bf(d) << 16));
  return lo | (hi << 32);
}
// LDS-only barrier: orders ds ops, leaves global loads in flight (T4).
static __device__ __forceinline__ void wg_barrier_lds() {
  asm volatile("s_waitcnt lgkmcnt(0)" ::: "memory");
  __builtin_amdgcn_s_barrier();
  asm volatile("" ::: "memory");
}

__global__ __launch_bounds__(512, 2)
void fpb_final(const float* __restrict__ x, const float* __restrict__ Ws,
               const float* __restrict__ Hsm, const float* __restrict__ Cs,
               float* __restrict__ out) {
  extern __shared__ char smem[];
  char* Y1F = smem;
  char* Zb  = smem + 49152;
  char* Cf  = smem + 98304;
  char* z16 = smem + 112128;

  int wid = (blockIdx.x & 7) * 128 + (blockIdx.x >> 3);  // XCD swizzle
  int window = wid >> 2, tile = wid & 3;
  int b = window >> 6, p = (window >> 3) & 7, q = window & 7;
  int j0 = tile * 16;

  int tid = threadIdx.x, lane = tid & 63, wave = tid >> 6;
  int lq = lane >> 4, lc = lane & 15;
  int mt = wave & 3, cp = wave >> 2;

  if (tid < 4) ((unsigned int*)z16)[tid] = 0;

  // Cf init: row (ss*3+m, lc), slot k = t*8+cl -> lane lq holds t=lq, e=cl
  for (int idx = wave; idx < 18; idx += 8) {
    int ss = idx / 3, m = idx - 3 * ss;
    if (lq < 3) {
      short8 v;
      #pragma unroll
      for (int e = 0; e < 8; ++e)
        v[e] = (short)f2bf(Cs[lq * 2304 + (8 * ss + e) * 48 + 16 * m + lc]);
      *(short8*)(Cf + (idx * 16 + lc) * 48 + lq * 16) = v;
    }
  }

  // persistent factor fragments
  short8 wsf[3][2], hsf[3][2];
  #pragma unroll
  for (int t = 0; t < 3; ++t)
    #pragma unroll
    for (int sv = 0; sv < 2; ++sv) {
      short8 aa, bb;
      #pragma unroll
      for (int e = 0; e < 8; ++e) {
        int k = 32 * sv + 8 * lq + e;
        aa[e] = (short)f2bf(Ws [t * 4096 + k * 64 + j0 + lc]);      // B: Ws[w][W']
        bb[e] = (short)f2bf(Hsm[t * 4096 + k * 64 + 16 * mt + lc]); // A: Hs^T[H'][h]
      }
      wsf[t][sv] = aa; hsf[t][sv] = bb;
    }

  float4v acc[3][8];
  #pragma unroll
  for (int m = 0; m < 3; ++m)
    #pragma unroll
    for (int i = 0; i < 8; ++i) acc[m][i] = float4v{0.f, 0.f, 0.f, 0.f};

  // A-stage: wave = c (within chunk); rows 16*mA+lc, cols 8*lq(+32)
  const float* xbase = x + (((size_t)b * 48) * 512 + p * 64) * 512 + q * 64
                         + (size_t)wave * 262144 + (size_t)lc * 512 + 8 * lq;

  float4v fin[2][8];   // two half-chunk prefetch slots
  #pragma unroll
  for (int h = 0; h < 2; ++h) {
    const float* src = xbase + (size_t)(32 * h) * 512;
    #pragma unroll
    for (int j2 = 0; j2 < 2; ++j2) {
      const float* r = src + (size_t)(16 * j2) * 512;
      fin[h][4*j2+0] = *(const float4v*)(r);
      fin[h][4*j2+1] = *(const float4v*)(r + 4);
      fin[h][4*j2+2] = *(const float4v*)(r + 32);
      fin[h][4*j2+3] = *(const float4v*)(r + 36);
    }
  }

  for (int s = 0; s < 6; ++s) {
    // ---- A: Y1F[t][c=wave] = X_c @ Ws_t (contract w); frag-major store ----
    #pragma unroll
    for (int h = 0; h < 2; ++h) {
      short8 af[4];
      #pragma unroll
      for (int j2 = 0; j2 < 2; ++j2) {
        short8 a0, a1;
        #pragma unroll
        for (int e2 = 0; e2 < 4; ++e2) {
          a0[e2]   = (short)f2bf(fin[h][4*j2+0][e2]);
          a0[4+e2] = (short)f2bf(fin[h][4*j2+1][e2]);
          a1[e2]   = (short)f2bf(fin[h][4*j2+2][e2]);
          a1[4+e2] = (short)f2bf(fin[h][4*j2+3][e2]);
        }
        af[2*j2] = a0; af[2*j2+1] = a1;
      }
      if (s < 5) {  // refill this slot for chunk s+1 (stays in flight across bars)
        const float* src = xbase + (size_t)(s + 1) * 2097152 + (size_t)(32 * h) * 512;
        #pragma unroll
        for (int j2 = 0; j2 < 2; ++j2) {
          const float* r = src + (size_t)(16 * j2) * 512;
          fin[h][4*j2+0] = *(const float4v*)(r);
          fin[h][4*j2+1] = *(const float4v*)(r + 4);
          fin[h][4*j2+2] = *(const float4v*)(r + 32);
          fin[h][4*j2+3] = *(const float4v*)(r + 36);
        }
      }
      #pragma unroll
      for (int j2 = 0; j2 < 2; ++j2) {
        int mA  = 2 * h + j2;
        int sv  = mA >> 1;
        int lqp = (2 * mA + (lq >> 1)) & 3;   // B-frag lane group (R5/R6-verified)
        int eo  = (lq & 1) * 8;
        #pragma unroll
        for (int t = 0; t < 3; ++t) {
          float4v d = {0.f, 0.f, 0.f, 0.f};
          d = __builtin_amdgcn_mfma_f32_16x16x32_bf16(af[2*j2],   wsf[t][0], d, 0, 0, 0);
          d = __builtin_amdgcn_mfma_f32_16x16x32_bf16(af[2*j2+1], wsf[t][1], d, 0, 0, 0);
          short4v pv;
          pv[0] = (short)f2bf(d[0]); pv[1] = (short)f2bf(d[1]);
          pv[2] = (short)f2bf(d[2]); pv[3] = (short)f2bf(d[3]);
          *(short4v*)(Y1F + ((t * 8 + wave) * 2 + sv) * 1024
                          + (lqp * 16 + lc) * 16 + eo) = pv;
        }
      }
    }
    wg_barrier_lds();

    // ---- B: Zb[px][k=t*8+cl] = Hs_t^T @ Y1F (contract h); linear frag reads ----
    #pragma unroll
    for (int t = 0; t < 3; ++t) {
      float4v dB[4];
      #pragma unroll
      for (int cj = 0; cj < 4; ++cj) {
        const char* yb = Y1F + ((t * 8 + 4 * cp + cj) * 2) * 1024 + lane * 16;
        short8 y0 = *(const short8*)yb;
        short8 y1 = *(const short8*)(yb + 1024);
        float4v dd = {0.f, 0.f, 0.f, 0.f};
        dd = __builtin_amdgcn_mfma_f32_16x16x32_bf16(hsf[t][0], y0, dd, 0, 0, 0);
        dd = __builtin_amdgcn_mfma_f32_16x16x32_bf16(hsf[t][1], y1, dd, 0, 0, 0);
        dB[cj] = dd;
      }
      #pragma unroll
      for (int r = 0; r < 4; ++r) {
        int px = (16 * mt + 4 * lq + r) * 16 + lc;
        *(unsigned long long*)(Zb + px * 48 + 16 * t + 8 * cp) =
            pk4(dB[0][r], dB[1][r], dB[2][r], dB[3][r]);
      }
    }
    wg_barrier_lds();

    // ---- C: acc += Cf @ Zb (contract t,c; K=32, slots 24..31 zero) ----
    {
      short8 cf[3];
      #pragma unroll
      for (int m = 0; m < 3; ++m) {
        const char* csrc = (lq < 3) ? (Cf + ((s * 3 + m) * 16 + lc) * 48 + lq * 16) : z16;
        cf[m] = *(const short8*)csrc;
      }
      #pragma unroll
      for (int i = 0; i < 8; ++i) {
        int px = 16 * (wave + 8 * i) + lc;
        const char* zsrc = (lq < 3) ? (Zb + px * 48 + 16 * lq) : z16;
        short8 zf = *(const short8*)zsrc;
        acc[0][i] = __builtin_amdgcn_mfma_f32_16x16x32_bf16(cf[0], zf, acc[0][i], 0, 0, 0);
        acc[1][i] = __builtin_amdgcn_mfma_f32_16x16x32_bf16(cf[1], zf, acc[1][i], 0, 0, 0);
        acc[2][i] = __builtin_amdgcn_mfma_f32_16x16x32_bf16(cf[2], zf, acc[2][i], 0, 0, 0);
      }
    }
    // no barrier: C's Zb reads complete before next bar1 orders next B's writes;
    // next A writes Y1F only (last read in B before bar2).
  }

  // ---- epilogue: fully static stores ----
  #pragma unroll
  for (int m = 0; m < 3; ++m)
    #pragma unroll
    for (int i = 0; i < 8; ++i) {
      int n = wave + 8 * i;
      size_t rowbase = (((size_t)(b * 48 + 16 * m + 4 * lq)) * 512 + p * 64 + n) * 512
                       + q * 64 + j0 + lc;
      #pragma unroll
      for (int r = 0; r < 4; ++r)
        out[rowbase + (size_t)r * 262144] = acc[m][i][r];
    }
}

extern "C" void kernel_launch(void* const* d_in, const int* in_sizes, int n_in,
                              void* d_out, int out_size, void* d_ws, size_t ws_size,
                              hipStream_t stream) {
  (void)in_sizes; (void)n_in; (void)d_ws; (void)ws_size; (void)out_size;
  const float* x   = (const float*)d_in[0];
  const float* Ws  = (const float*)d_in[1];
  const float* Hsm = (const float*)d_in[2];
  const float* Cs  = (const float*)d_in[3];
  float* out = (float*)d_out;
  (void)hipFuncSetAttribute((const void*)fpb_final,
                            hipFuncAttributeMaxDynamicSharedMemorySize, SMEM_BYTES);
  fpb_final<<<dim3(1024), dim3(512), SMEM_BYTES, stream>>>(x, Ws, Hsm, Cs, out);
}